// Round 1
// baseline (419.779 us; speedup 1.0000x reference)
//
#include <hip/hip_runtime.h>
#include <hip/hip_bf16.h>
#include <stdint.h>

// ---------------------------------------------------------------------------
// STE ternary linear: out = x @ q^T, q = ternary(weight, thr=0.05*mean|w|)
// x: [8192, 4096] fp32, weight: [4096, 4096] fp32, out: [8192, 4096] fp32
//
// R1: bf16 m97 GEMM 316us @ 870 TF (plateau), absmax 2.0. prep gap ~240us.
// R2: prep fusion NEUTRAL -> gap ~246us is mostly fixed harness overhead
//     (restore/poison), not prep execution. GEMM is the only big lever.
// R3: i8 GEMM. q exact in i8; x per-row absmax-scaled to i8 (err ~3.5 max,
//     thr 7.08). mfma_i32_16x16x64_i8: 2x ops/inst, half staging bytes,
//     half MFMA count -> both plateau terms shrink 2x. Predicted ~170-210us.
// R4: resubmit of R3 — previous bench was an infra failure (container died
//     twice), no counters. Kernel re-audited (staging layout, frag layout,
//     C/D mapping, scale math) — unchanged.
// ---------------------------------------------------------------------------

typedef __attribute__((ext_vector_type(4))) int i32x4;

#define BM 128
#define BN 128
#define BKB 64          // K-bytes per tile (i8) = K elems per MFMA

#define M_ROWS 8192     // x rows (blocks 0..M_ROWS-1 in prep)
#define ABS_BLOCKS 1024 // w abs-mean blocks

__device__ inline void gld_lds16(const void* g, void* l) {
  // 16B per lane, LDS dest = wave-uniform base + lane*16
  __builtin_amdgcn_global_load_lds(
      (__attribute__((address_space(1))) void*)g,
      (__attribute__((address_space(3))) void*)l,
      16, 0, 0);
}

__device__ inline int pack4(int a, int b, int c, int d) {
  return (a & 255) | ((b & 255) << 8) | ((c & 255) << 16) | (d << 24);
}

__device__ inline int q8(float v, float inv) {
  int q = __float2int_rn(v * inv);
  return q > 127 ? 127 : (q < -127 ? -127 : q);
}

// ---------------- fused prep: per-row x quant || w abs-mean -----------------
// blocks [0, M_ROWS): one block per x row. absmax from registers, quantize
//   in the same pass (x read once). steps[row] = rowmax/127.
// blocks [M_ROWS, M_ROWS+ABS_BLOCKS): fp64 abs-sum of w -> atomicAdd.
__global__ __launch_bounds__(256) void prep_kernel(
    const float4* __restrict__ x, signed char* __restrict__ xq,
    float* __restrict__ steps, const float4* __restrict__ w, int wn4,
    double* __restrict__ sum) {
  if (blockIdx.x < M_ROWS) {
    const int row = blockIdx.x;
    const float4* xr = x + (size_t)row * 1024;  // 4096 floats = 1024 float4
    float4 v[4];
    float amax = 0.0f;
#pragma unroll
    for (int j = 0; j < 4; ++j) {
      v[j] = xr[threadIdx.x + 256 * j];
      amax = fmaxf(amax, fmaxf(fmaxf(fabsf(v[j].x), fabsf(v[j].y)),
                               fmaxf(fabsf(v[j].z), fabsf(v[j].w))));
    }
#pragma unroll
    for (int off = 32; off > 0; off >>= 1)
      amax = fmaxf(amax, __shfl_down(amax, off, 64));
    __shared__ float wmax[4];
    const int lane = threadIdx.x & 63, wave = threadIdx.x >> 6;
    if (lane == 0) wmax[wave] = amax;
    __syncthreads();
    const float m = fmaxf(fmaxf(wmax[0], wmax[1]), fmaxf(wmax[2], wmax[3]));
    const float inv = m > 0.0f ? 127.0f / m : 0.0f;
    if (threadIdx.x == 0) steps[row] = m > 0.0f ? m / 127.0f : 0.0f;
    int* out = (int*)(xq + (size_t)row * 4096);
#pragma unroll
    for (int j = 0; j < 4; ++j) {
      out[threadIdx.x + 256 * j] = pack4(q8(v[j].x, inv), q8(v[j].y, inv),
                                         q8(v[j].z, inv), q8(v[j].w, inv));
    }
  } else {
    double s = 0.0;
    const int stride = ABS_BLOCKS * 256;
    for (int i = (blockIdx.x - M_ROWS) * 256 + threadIdx.x; i < wn4;
         i += stride) {
      float4 v = w[i];
      s += (double)((fabsf(v.x) + fabsf(v.y)) + (fabsf(v.z) + fabsf(v.w)));
    }
#pragma unroll
    for (int off = 32; off > 0; off >>= 1) s += __shfl_down(s, off, 64);
    __shared__ double wsum[4];
    const int lane = threadIdx.x & 63, wave = threadIdx.x >> 6;
    if (lane == 0) wsum[wave] = s;
    __syncthreads();
    if (threadIdx.x == 0) atomicAdd(sum, wsum[0] + wsum[1] + wsum[2] + wsum[3]);
  }
}

// ---------------- ternary quantize weight -> i8 {-1,0,+1} -------------------
__global__ __launch_bounds__(256) void quant_kernel(
    const float4* __restrict__ w, const double* __restrict__ sum,
    int* __restrict__ q, int n4, double inv_n) {
  const float thr = (float)(0.05 * (*sum) * inv_n);
  const int stride = gridDim.x * blockDim.x;
  for (int i = blockIdx.x * blockDim.x + threadIdx.x; i < n4; i += stride) {
    float4 v = w[i];
    int a = v.x > thr ? 1 : (v.x < -thr ? -1 : 0);
    int b = v.y > thr ? 1 : (v.y < -thr ? -1 : 0);
    int c = v.z > thr ? 1 : (v.z < -thr ? -1 : 0);
    int d = v.w > thr ? 1 : (v.w < -thr ? -1 : 0);
    q[i] = pack4(a, b, c, d);
  }
}

// ---------------- i8 GEMM, B^T layout (m97 structure, K=64/MFMA) ------------
// A: [M][K] i8, B: [N][K] i8, C: [M][N] fp32 = i32acc * steps[m]
// block = 256 threads = 4 waves (2x2), each wave 64x64 out via 4x4 MFMA tiles
// A-frag: row = lane&15, k = (lane>>4)*16 + j (16B contiguous = 1 ds_read_b128)
// C/D: row = (lane>>4)*4 + r, col = lane&15 (dtype-independent, m121-128)
__global__ __launch_bounds__(256, 2) void gemm_i8(
    const signed char* __restrict__ A, const signed char* __restrict__ B,
    const float* __restrict__ steps, float* __restrict__ C, int M, int N,
    int K) {
  __shared__ unsigned char As[BM * BKB];  // 8 KiB
  __shared__ unsigned char Bs[BN * BKB];  // 8 KiB

  const int tid = threadIdx.x;
  const int lane = tid & 63;
  const int wave = tid >> 6;

  const int bm = blockIdx.y * BM;
  const int bn = blockIdx.x * BN;

  // staging: tile = 8 KiB = 8 chunks x 1024B; wave w handles chunks 2w,2w+1
  // chunk c: rows [16c,16c+16); lane l -> row 16c + l/4, byte (l&3)*16
  const int ca0 = wave * 2;
  const int ca1 = wave * 2 + 1;
  const int rl = lane >> 2;
  const int bo = (lane & 3) * 16;

  const signed char* a0 = A + (size_t)(bm + ca0 * 16 + rl) * K + bo;
  const signed char* a1 = A + (size_t)(bm + ca1 * 16 + rl) * K + bo;
  const signed char* b0 = B + (size_t)(bn + ca0 * 16 + rl) * K + bo;
  const signed char* b1 = B + (size_t)(bn + ca1 * 16 + rl) * K + bo;

  unsigned char* la0 = &As[ca0 * 1024];
  unsigned char* la1 = &As[ca1 * 1024];
  unsigned char* lb0 = &Bs[ca0 * 1024];
  unsigned char* lb1 = &Bs[ca1 * 1024];

  const int wm = (wave >> 1) * 64;  // wave 2x2 grid over 128x128
  const int wn = (wave & 1) * 64;

  const int fr = lane & 15;          // fragment row (m or n within 16-tile)
  const int fk = (lane >> 4) * 16;   // fragment k byte offset

  i32x4 acc[4][4] = {};

  for (int k0 = 0; k0 < K; k0 += BKB) {
    gld_lds16(a0 + k0, la0);
    gld_lds16(a1 + k0, la1);
    gld_lds16(b0 + k0, lb0);
    gld_lds16(b1 + k0, lb1);
    __syncthreads();

    i32x4 af[4], bfr[4];
#pragma unroll
    for (int i = 0; i < 4; ++i) {
      af[i]  = *(const i32x4*)(&As[(wm + i * 16 + fr) * BKB + fk]);
      bfr[i] = *(const i32x4*)(&Bs[(wn + i * 16 + fr) * BKB + fk]);
    }
#pragma unroll
    for (int mi = 0; mi < 4; ++mi)
#pragma unroll
      for (int ni = 0; ni < 4; ++ni)
        acc[mi][ni] = __builtin_amdgcn_mfma_i32_16x16x64_i8(
            af[mi], bfr[ni], acc[mi][ni], 0, 0, 0);
    __syncthreads();
  }

  // epilogue: out = i32acc * steps[m]
  const int cn = lane & 15;
  const int cm = (lane >> 4) * 4;
  float st[4][4];
#pragma unroll
  for (int mi = 0; mi < 4; ++mi)
#pragma unroll
    for (int r = 0; r < 4; ++r)
      st[mi][r] = steps[bm + wm + mi * 16 + cm + r];
#pragma unroll
  for (int mi = 0; mi < 4; ++mi) {
#pragma unroll
    for (int ni = 0; ni < 4; ++ni) {
#pragma unroll
      for (int r = 0; r < 4; ++r) {
        int m = bm + wm + mi * 16 + cm + r;
        int n = bn + wn + ni * 16 + cn;
        C[(size_t)m * N + n] = (float)acc[mi][ni][r] * st[mi][r];
      }
    }
  }
}

// ---------------------------------------------------------------------------
extern "C" void kernel_launch(void* const* d_in, const int* in_sizes, int n_in,
                              void* d_out, int out_size, void* d_ws,
                              size_t ws_size, hipStream_t stream) {
  const float* x = (const float*)d_in[0];
  const float* w = (const float*)d_in[1];
  float* out = (float*)d_out;

  const int K = 4096;
  const int N = 4096;
  const int M = in_sizes[0] / K;   // 8192
  const int NW = in_sizes[1];      // 4096*4096

  char* ws = (char*)d_ws;
  double* d_sum = (double*)ws;                               // 8 B
  float* steps = (float*)(ws + 256);                         // M floats (32 KB)
  signed char* qb = (signed char*)(ws + 65536);              // N*K i8 (16.8 MB)
  signed char* xq = qb + (size_t)N * K;                      // M*K i8 (33.6 MB)

  hipMemsetAsync(d_sum, 0, sizeof(double), stream);
  prep_kernel<<<M_ROWS + ABS_BLOCKS, 256, 0, stream>>>(
      (const float4*)x, xq, steps, (const float4*)w, NW / 4, d_sum);
  quant_kernel<<<2048, 256, 0, stream>>>((const float4*)w, d_sum, (int*)qb,
                                         NW / 4, 1.0 / NW);
  dim3 grid(N / BN, M / BM);
  gemm_i8<<<grid, 256, 0, stream>>>(xq, qb, steps, out, M, N, K);
}

// Round 3
// 389.191 us; speedup vs baseline: 1.0786x; 1.0786x over previous
//
#include <hip/hip_runtime.h>
#include <hip/hip_bf16.h>
#include <stdint.h>

// ---------------------------------------------------------------------------
// STE ternary linear: out = x @ q^T, q = ternary(weight, thr=0.05*mean|w|)
// x: [8192, 4096] fp32, weight: [4096, 4096] fp32, out: [8192, 4096] fp32
//
// R1: bf16 m97 GEMM 316us @ 870 TF (plateau), absmax 2.0.
// R3/R4: i8 m97 GEMM 165us, MfmaUtil 37.5%, BANK_CONFLICT 1.7e7 -> the known
//     m97-structure plateau, faithfully reproduced in i8. total 419.8us.
// R5: 8-phase 256^2 schedule (T2+T3+T4+T5), i8 port of the m201 template.
//     BK=128 i8 = 128B/row (byte-isomorphic to bf16 BK=64). LDS XOR-swizzle
//     col^=(row&7)<<4 via inverse-swizzled global source (linear gld_lds
//     dest) + swizzled ds_read. Counted vmcnt: (2) at tile-end, (4) mid-tile,
//     never 0 in steady state. setprio(1) around MFMA cluster.
//     Predicted: gemm 165 -> ~100us, MfmaUtil ~60%, conflicts <1e6.
// R6: resubmit of R5 — infra failure (container died twice, same as R0->R1).
//     Re-audited for hang paths: uniform barriers, satisfiable vmcnt ledger,
//     LDS/global bounds, swizzle bijectivity, bank pattern. Unchanged.
// ---------------------------------------------------------------------------

typedef __attribute__((ext_vector_type(4))) int i32x4;

#define KDIM 4096
#define NDIM 4096

#define M_ROWS 8192     // x rows (blocks 0..M_ROWS-1 in prep)
#define ABS_BLOCKS 1024 // w abs-mean blocks

__device__ inline void gld_lds16(const void* g, void* l) {
  // 16B per lane, LDS dest = wave-uniform base + lane*16
  __builtin_amdgcn_global_load_lds(
      (__attribute__((address_space(1))) void*)g,
      (__attribute__((address_space(3))) void*)l,
      16, 0, 0);
}

__device__ inline int pack4(int a, int b, int c, int d) {
  return (a & 255) | ((b & 255) << 8) | ((c & 255) << 16) | (d << 24);
}

__device__ inline int q8(float v, float inv) {
  int q = __float2int_rn(v * inv);
  return q > 127 ? 127 : (q < -127 ? -127 : q);
}

// ---------------- fused prep: per-row x quant || w abs-mean -----------------
__global__ __launch_bounds__(256) void prep_kernel(
    const float4* __restrict__ x, signed char* __restrict__ xq,
    float* __restrict__ steps, const float4* __restrict__ w, int wn4,
    double* __restrict__ sum) {
  if (blockIdx.x < M_ROWS) {
    const int row = blockIdx.x;
    const float4* xr = x + (size_t)row * 1024;  // 4096 floats = 1024 float4
    float4 v[4];
    float amax = 0.0f;
#pragma unroll
    for (int j = 0; j < 4; ++j) {
      v[j] = xr[threadIdx.x + 256 * j];
      amax = fmaxf(amax, fmaxf(fmaxf(fabsf(v[j].x), fabsf(v[j].y)),
                               fmaxf(fabsf(v[j].z), fabsf(v[j].w))));
    }
#pragma unroll
    for (int off = 32; off > 0; off >>= 1)
      amax = fmaxf(amax, __shfl_down(amax, off, 64));
    __shared__ float wmax[4];
    const int lane = threadIdx.x & 63, wave = threadIdx.x >> 6;
    if (lane == 0) wmax[wave] = amax;
    __syncthreads();
    const float m = fmaxf(fmaxf(wmax[0], wmax[1]), fmaxf(wmax[2], wmax[3]));
    const float inv = m > 0.0f ? 127.0f / m : 0.0f;
    if (threadIdx.x == 0) steps[row] = m > 0.0f ? m / 127.0f : 0.0f;
    int* out = (int*)(xq + (size_t)row * 4096);
#pragma unroll
    for (int j = 0; j < 4; ++j) {
      out[threadIdx.x + 256 * j] = pack4(q8(v[j].x, inv), q8(v[j].y, inv),
                                         q8(v[j].z, inv), q8(v[j].w, inv));
    }
  } else {
    double s = 0.0;
    const int stride = ABS_BLOCKS * 256;
    for (int i = (blockIdx.x - M_ROWS) * 256 + threadIdx.x; i < wn4;
         i += stride) {
      float4 v = w[i];
      s += (double)((fabsf(v.x) + fabsf(v.y)) + (fabsf(v.z) + fabsf(v.w)));
    }
#pragma unroll
    for (int off = 32; off > 0; off >>= 1) s += __shfl_down(s, off, 64);
    __shared__ double wsum[4];
    const int lane = threadIdx.x & 63, wave = threadIdx.x >> 6;
    if (lane == 0) wsum[wave] = s;
    __syncthreads();
    if (threadIdx.x == 0) atomicAdd(sum, wsum[0] + wsum[1] + wsum[2] + wsum[3]);
  }
}

// ---------------- ternary quantize weight -> i8 {-1,0,+1} -------------------
__global__ __launch_bounds__(256) void quant_kernel(
    const float4* __restrict__ w, const double* __restrict__ sum,
    int* __restrict__ q, int n4, double inv_n) {
  const float thr = (float)(0.05 * (*sum) * inv_n);
  const int stride = gridDim.x * blockDim.x;
  for (int i = blockIdx.x * blockDim.x + threadIdx.x; i < n4; i += stride) {
    float4 v = w[i];
    int a = v.x > thr ? 1 : (v.x < -thr ? -1 : 0);
    int b = v.y > thr ? 1 : (v.y < -thr ? -1 : 0);
    int c = v.z > thr ? 1 : (v.z < -thr ? -1 : 0);
    int d = v.w > thr ? 1 : (v.w < -thr ? -1 : 0);
    q[i] = pack4(a, b, c, d);
  }
}

// ---------------- i8 GEMM, 256^2 8-phase schedule ---------------------------
// A: [M][4096] i8, B: [4096][4096] i8 (row = out col), C = i32acc * steps[m]
// 512 thr = 8 waves (2M x 4N); per-wave out 128x64 = acc[8][4] i32x4.
// LDS [2buf][256 rows][128 B] for A and B (128 KiB). K-tile = 128 i8.
// Swizzle: LDS(r, c) holds global(r, c ^ ((r&7)<<4)); gld_lds dest linear,
// source col pre-swizzled per lane; ds_read applies same XOR.
// Per K-tile 4 phases (q = C-row-quadrant): read 4 A-frags (+8 B-frags @q0),
// stage 2 half-tile loads of tile t+1 (order Bh0,Bh1,A-L0s,A-L1s), barrier,
// lgkmcnt(0), 16 MFMA in setprio(1). vmcnt(4) end of q1 (A-L1s of t landed),
// vmcnt(2) end of q3 (B + A-L0s of t+1 landed). In-flight <= 8, never drained
// to 0 mid-loop. All LDS overwrites >= 4 phases after last reader.
#define MFMA_I8 __builtin_amdgcn_mfma_i32_16x16x64_i8

__global__ __launch_bounds__(512, 2) void gemm_i8_8p(
    const signed char* __restrict__ A, const signed char* __restrict__ B,
    const float* __restrict__ steps, float* __restrict__ C, int M) {
  __shared__ unsigned char lds[131072];  // A buf@0 (64K), B buf@65536 (64K)

  const int tid = threadIdx.x;
  const int lane = tid & 63;
  const int w = tid >> 6;

  const int bm = blockIdx.y * 256;
  const int bn = blockIdx.x * 256;

  // ---- staging addressing: lane -> row (w*8 + lane>>3), col (lane&7)*16 ----
  const int rL = lane >> 3;                   // 0..7 within wave's 8 rows
  const int csw = (((lane & 7) ^ rL) << 4);   // inverse-swizzled source col
  const signed char* aBase = A + (size_t)(bm + w * 8 + rL) * KDIM + csw;
  const signed char* bBase = B + (size_t)(bn + w * 8 + rL) * KDIM + csw;
  unsigned char* const ldsA = lds;
  unsigned char* const ldsB = lds + 65536;
  // dest offsets: half h -> +h*16384, load j -> +j*8192, wave -> +w*1024
  // global row offsets: half h -> +h*128*KDIM, load j -> +j*64*KDIM

  // ---- fragment read addressing ----
  const int fr = lane & 15;                 // row within 16-tile
  const int fk = (lane >> 4) * 16;          // k-byte subslice
  const int xr = (lane & 7) << 4;           // read-side swizzle (= (row&7)<<4)
  const int cc0 = fk ^ xr;                  // kk=0 col
  const int cc1 = (64 + fk) ^ xr;           // kk=1 col
  const int wm = (w >> 2) * 128;            // wave M offset (2 rows of waves)
  const int wn = (w & 3) * 64;              // wave N offset (4 cols of waves)
  const int aro = (wm + fr) * 128;
  const int bro = (wn + fr) * 128;

  i32x4 acc[8][4] = {};

  // ---- prologue: stage tile 0 into buf 0 (order: B h0,h1; A L0s; A L1s) ----
  gld_lds16(bBase, ldsB + w * 1024);
  gld_lds16(bBase + (size_t)64 * KDIM, ldsB + 8192 + w * 1024);
  gld_lds16(bBase + (size_t)128 * KDIM, ldsB + 16384 + w * 1024);
  gld_lds16(bBase + (size_t)192 * KDIM, ldsB + 16384 + 8192 + w * 1024);
  gld_lds16(aBase, ldsA + w * 1024);
  gld_lds16(aBase + (size_t)128 * KDIM, ldsA + 16384 + w * 1024);
  gld_lds16(aBase + (size_t)64 * KDIM, ldsA + 8192 + w * 1024);
  gld_lds16(aBase + (size_t)192 * KDIM, ldsA + 16384 + 8192 + w * 1024);
  asm volatile("s_waitcnt vmcnt(2)" ::: "memory");  // B + A-L0s landed
  __builtin_amdgcn_s_barrier();

  for (int t = 0; t < 32; ++t) {
    const int b = t & 1;
    const bool st = (t < 31);
    const unsigned char* Ab = ldsA + b * 32768;
    const unsigned char* Bb = ldsB + b * 32768;
    unsigned char* An = ldsA + (b ^ 1) * 32768;
    unsigned char* Bn = ldsB + (b ^ 1) * 32768;
    const signed char* aS = aBase + (size_t)(t + 1) * 128;
    const signed char* bS = bBase + (size_t)(t + 1) * 128;

    i32x4 bfr[4][2];

#pragma unroll
    for (int q = 0; q < 4; ++q) {
      // --- ds-reads for this phase ---
      if (q == 0) {
#pragma unroll
        for (int ni = 0; ni < 4; ++ni) {
          bfr[ni][0] = *(const i32x4*)(Bb + bro + ni * 2048 + cc0);
          bfr[ni][1] = *(const i32x4*)(Bb + bro + ni * 2048 + cc1);
        }
      }
      i32x4 a00 = *(const i32x4*)(Ab + aro + (2 * q) * 2048 + cc0);
      i32x4 a01 = *(const i32x4*)(Ab + aro + (2 * q) * 2048 + cc1);
      i32x4 a10 = *(const i32x4*)(Ab + aro + (2 * q + 1) * 2048 + cc0);
      i32x4 a11 = *(const i32x4*)(Ab + aro + (2 * q + 1) * 2048 + cc1);

      // --- stage tile t+1 (2 gld_lds per phase) ---
      if (st) {
        if (q == 0) {
          gld_lds16(bS, Bn + w * 1024);
          gld_lds16(bS + (size_t)64 * KDIM, Bn + 8192 + w * 1024);
        } else if (q == 1) {
          gld_lds16(bS + (size_t)128 * KDIM, Bn + 16384 + w * 1024);
          gld_lds16(bS + (size_t)192 * KDIM, Bn + 16384 + 8192 + w * 1024);
        } else if (q == 2) {
          gld_lds16(aS, An + w * 1024);
          gld_lds16(aS + (size_t)128 * KDIM, An + 16384 + w * 1024);
        } else {
          gld_lds16(aS + (size_t)64 * KDIM, An + 8192 + w * 1024);
          gld_lds16(aS + (size_t)192 * KDIM, An + 16384 + 8192 + w * 1024);
        }
      }

      __builtin_amdgcn_s_barrier();
      asm volatile("s_waitcnt lgkmcnt(0)" ::: "memory");
      __builtin_amdgcn_s_setprio(1);
#pragma unroll
      for (int ni = 0; ni < 4; ++ni) {
        acc[2 * q][ni] = MFMA_I8(a00, bfr[ni][0], acc[2 * q][ni], 0, 0, 0);
        acc[2 * q][ni] = MFMA_I8(a01, bfr[ni][1], acc[2 * q][ni], 0, 0, 0);
        acc[2 * q + 1][ni] =
            MFMA_I8(a10, bfr[ni][0], acc[2 * q + 1][ni], 0, 0, 0);
        acc[2 * q + 1][ni] =
            MFMA_I8(a11, bfr[ni][1], acc[2 * q + 1][ni], 0, 0, 0);
      }
      __builtin_amdgcn_s_setprio(0);

      if (q == 1) {
        if (st)
          asm volatile("s_waitcnt vmcnt(4)" ::: "memory");  // t's A-L1s landed
        else
          asm volatile("s_waitcnt vmcnt(0)" ::: "memory");  // tail drain
      }
      if (q == 3 && st)
        asm volatile("s_waitcnt vmcnt(2)" ::: "memory");  // t+1 B+A-L0s landed
      __builtin_amdgcn_s_barrier();
    }
  }

  // ---- epilogue: out = i32acc * steps[m] ----
  const int cn = lane & 15;
  const int cm = (lane >> 4) * 4;
  float stp[8][4];
#pragma unroll
  for (int mi = 0; mi < 8; ++mi)
#pragma unroll
    for (int r = 0; r < 4; ++r)
      stp[mi][r] = steps[bm + wm + mi * 16 + cm + r];
#pragma unroll
  for (int mi = 0; mi < 8; ++mi) {
#pragma unroll
    for (int ni = 0; ni < 4; ++ni) {
#pragma unroll
      for (int r = 0; r < 4; ++r) {
        const int m = bm + wm + mi * 16 + cm + r;
        const int n = bn + wn + ni * 16 + cn;
        C[(size_t)m * NDIM + n] = (float)acc[mi][ni][r] * stp[mi][r];
      }
    }
  }
}

// ---------------------------------------------------------------------------
extern "C" void kernel_launch(void* const* d_in, const int* in_sizes, int n_in,
                              void* d_out, int out_size, void* d_ws,
                              size_t ws_size, hipStream_t stream) {
  const float* x = (const float*)d_in[0];
  const float* w = (const float*)d_in[1];
  float* out = (float*)d_out;

  const int K = 4096;
  const int N = 4096;
  const int M = in_sizes[0] / K;   // 8192
  const int NW = in_sizes[1];      // 4096*4096

  char* ws = (char*)d_ws;
  double* d_sum = (double*)ws;                               // 8 B
  float* steps = (float*)(ws + 256);                         // M floats (32 KB)
  signed char* qb = (signed char*)(ws + 65536);              // N*K i8 (16.8 MB)
  signed char* xq = qb + (size_t)N * K;                      // M*K i8 (33.6 MB)

  hipMemsetAsync(d_sum, 0, sizeof(double), stream);
  prep_kernel<<<M_ROWS + ABS_BLOCKS, 256, 0, stream>>>(
      (const float4*)x, xq, steps, (const float4*)w, NW / 4, d_sum);
  quant_kernel<<<2048, 256, 0, stream>>>((const float4*)w, d_sum, (int*)qb,
                                         NW / 4, 1.0 / NW);
  dim3 grid(N / 256, M / 256);
  gemm_i8_8p<<<grid, 512, 0, stream>>>(xq, qb, steps, out, M);
}